// Round 11
// baseline (258.716 us; speedup 1.0000x reference)
//
#include <hip/hip_runtime.h>
#include <hip/hip_bf16.h>

#define M_NODES  50000
#define D_IN_K   512
#define D_OUT_N  128
#define N_EDGES  800000
#define SCAN_NBLK 49   // ceil(50000/1024)

typedef short  bf16x8 __attribute__((ext_vector_type(8)));
typedef float  f32x4  __attribute__((ext_vector_type(4)));

static __device__ __forceinline__ unsigned short f2bf(float f) {
    unsigned u = __float_as_uint(f);
    unsigned r = u + 0x7FFF + ((u >> 16) & 1);   // RNE
    return (unsigned short)(r >> 16);
}
static __device__ __forceinline__ float bflo(unsigned q) { return __uint_as_float(q << 16); }
static __device__ __forceinline__ float bfhi(unsigned q) { return __uint_as_float(q & 0xFFFF0000u); }

// ---------------------------------------------------------------------------
// Permute W (fp32 [512][128]) into bf16 B-fragment order (uint4 frags).
// Also zeroes counts+flags (50064 ints) -> no memset dispatch.
// ---------------------------------------------------------------------------
__global__ __launch_bounds__(256) void permw_kernel(const float* __restrict__ W,
                                                    unsigned short* __restrict__ Wp,
                                                    int* __restrict__ counts) {
    int tid = blockIdx.x * 256 + threadIdx.x;  // 0..8191
    int lane = tid & 63;
    int nt   = (tid >> 6) & 7;
    int kb4  = tid >> 9;
    int n    = nt * 16 + (lane & 15);
    int kbase = kb4 * 32 + ((lane >> 4) & 3) * 8;
    unsigned short frag[8];
#pragma unroll
    for (int j = 0; j < 8; ++j)
        frag[j] = f2bf(W[(size_t)(kbase + j) * D_OUT_N + n]);
    *(uint4*)&Wp[(size_t)tid * 8] = *(const uint4*)frag;

    // zero counts (50000) + flags (64), contiguous in workspace
    for (int i = tid; i < M_NODES + 64; i += 8192) counts[i] = 0;
}

// ---------------------------------------------------------------------------
// h(bf16) = x @ W, 512 threads (8 waves x 16 rows, round-10 proven) with the
// histogram tail converted to T14 issue-early/consume-late: 4 consecutive
// edges per thread, dst loaded + 4 atomicAdds fired at KERNEL ENTRY, return
// values (ranks) held in VGPRs through the GEMM, int4 rank store in the
// epilogue. Atomic latency + coherence-point drain overlap the ~30us GEMM
// instead of extending the kernel.
// ---------------------------------------------------------------------------
__global__ __launch_bounds__(512, 4) void mfma_gemm_hist_kernel(const float* __restrict__ x,
                                                                const uint4* __restrict__ Wp4,
                                                                unsigned short* __restrict__ h,
                                                                const int* __restrict__ dst,
                                                                int* __restrict__ counts,
                                                                int* __restrict__ rank) {
    __shared__ uint4 wlds[4096];              // 64 KB: [kb 8][nt 8][lane 64]

    const int tid  = threadIdx.x;
    const int wave = tid >> 6;                // 0..7
    const int lane = tid & 63;
    const int m0   = blockIdx.x * 128 + wave * 16;
    const int mrow = lane & 15;
    const int kgrp = lane >> 4;               // 0..3

    // --- histogram: issue-early (independent of GEMM) ---
    const int ebase = (blockIdx.x * 512 + tid) * 4;   // 391*512*4 >= 800000
    int4 r4;
    const bool edo = ebase < N_EDGES;                 // N_EDGES%4==0 -> full quad
    if (edo) {
        int4 d4 = *(const int4*)&dst[ebase];
        r4.x = atomicAdd(&counts[d4.x], 1);
        r4.y = atomicAdd(&counts[d4.y], 1);
        r4.z = atomicAdd(&counts[d4.z], 1);
        r4.w = atomicAdd(&counts[d4.w], 1);
    }

    const int r0 = m0 + mrow;
    const float* xr0 = x + (size_t)((r0 < M_NODES) ? r0 : M_NODES - 1) * D_IN_K + kgrp * 8;

    f32x4 acc[8];
#pragma unroll
    for (int t = 0; t < 8; ++t) acc[t] = (f32x4){0.f, 0.f, 0.f, 0.f};

    for (int half = 0; half < 2; ++half) {
        __syncthreads();
#pragma unroll
        for (int i = 0; i < 8; ++i)
            wlds[tid + i * 512] = Wp4[half * 4096 + tid + i * 512];
        __syncthreads();

        const float* px0 = xr0 + half * 256;

        float4 a00 = *(const float4*)(px0);
        float4 a01 = *(const float4*)(px0 + 4);

#pragma unroll
        for (int kb = 0; kb < 8; ++kb) {
            float4 n00, n01;
            if (kb < 7) {
                n00 = *(const float4*)(px0 + (kb + 1) * 32);
                n01 = *(const float4*)(px0 + (kb + 1) * 32 + 4);
            }

            union { bf16x8 v; __hip_bfloat162 h2[4]; } c0;
            c0.h2[0] = __float22bfloat162_rn(make_float2(a00.x, a00.y));
            c0.h2[1] = __float22bfloat162_rn(make_float2(a00.z, a00.w));
            c0.h2[2] = __float22bfloat162_rn(make_float2(a01.x, a01.y));
            c0.h2[3] = __float22bfloat162_rn(make_float2(a01.z, a01.w));
            bf16x8 a0 = c0.v;

#pragma unroll
            for (int nt = 0; nt < 8; ++nt) {
                union { uint4 u; bf16x8 v; } wb;
                wb.u = wlds[(kb * 8 + nt) * 64 + lane];
                acc[nt] = __builtin_amdgcn_mfma_f32_16x16x32_bf16(a0, wb.v, acc[nt], 0, 0, 0);
            }

            if (kb < 7) { a00 = n00; a01 = n01; }
        }
    }

    // epilogue: C/D layout col=lane&15, row=kgrp*4+r
#pragma unroll
    for (int r = 0; r < 4; ++r) {
        int rr = m0 + kgrp * 4 + r;
        if (rr < M_NODES) {
            unsigned short* hp = h + (size_t)rr * D_OUT_N + mrow;
#pragma unroll
            for (int nt = 0; nt < 8; ++nt)
                hp[nt * 16] = f2bf(acc[nt][r]);
        }
    }

    // --- histogram: consume-late (ranks held in VGPRs since entry) ---
    if (edo) *(int4*)&rank[ebase] = r4;
}

// ---------------------------------------------------------------------------
// Single-launch exclusive scan (49 co-resident blocks, lookback on flags).
// ---------------------------------------------------------------------------
__global__ __launch_bounds__(256) void scan_kernel(const int* __restrict__ counts,
                                                   int* __restrict__ offsets,
                                                   int* __restrict__ partials,
                                                   int* __restrict__ flags) {
    __shared__ int wsum[4];
    __shared__ int carry_s;
    const int tid  = threadIdx.x;
    const int lane = tid & 63;
    const int wid  = tid >> 6;
    const int blk  = blockIdx.x;
    const int base = blk * 1024 + tid * 4;

    int v[4];
    if (base + 3 < M_NODES) {
        int4 q = *(const int4*)&counts[base];
        v[0] = q.x; v[1] = q.y; v[2] = q.z; v[3] = q.w;
    } else {
#pragma unroll
        for (int i = 0; i < 4; ++i)
            v[i] = (base + i < M_NODES) ? counts[base + i] : 0;
    }
    int t = v[0] + v[1] + v[2] + v[3];

    int s = t;
#pragma unroll
    for (int d = 1; d < 64; d <<= 1) {
        int u = __shfl_up(s, d, 64);
        if (lane >= d) s += u;
    }
    if (lane == 63) wsum[wid] = s;
    __syncthreads();
    int wbase = 0;
#pragma unroll
    for (int w = 0; w < 4; ++w) wbase += (w < wid) ? wsum[w] : 0;
    int total = wsum[0] + wsum[1] + wsum[2] + wsum[3];

    if (tid == 0) {
        __hip_atomic_store(&partials[blk], total, __ATOMIC_RELAXED, __HIP_MEMORY_SCOPE_AGENT);
        __hip_atomic_store(&flags[blk], 1, __ATOMIC_RELEASE, __HIP_MEMORY_SCOPE_AGENT);
        if (blk == 0) offsets[M_NODES] = N_EDGES;
    }

    if (wid == 0) {
        int val = 0;
        if (lane < blk) {
            while (__hip_atomic_load(&flags[lane], __ATOMIC_ACQUIRE, __HIP_MEMORY_SCOPE_AGENT) == 0) {}
            val = __hip_atomic_load(&partials[lane], __ATOMIC_RELAXED, __HIP_MEMORY_SCOPE_AGENT);
        }
#pragma unroll
        for (int d = 32; d > 0; d >>= 1) val += __shfl_xor(val, d, 64);
        if (lane == 0) carry_s = val;
    }
    __syncthreads();
    const int carry = carry_s;

    int run = carry + wbase + s - t;   // exclusive prefix for this thread's 4 nodes
#pragma unroll
    for (int i = 0; i < 4; ++i) {
        if (base + i < M_NODES) offsets[base + i] = run;
        run += v[i];
    }
}

// ---------------------------------------------------------------------------
// Permute edges into CSR order — ATOMIC-FREE: pos = offsets[dst] + rank.
// ---------------------------------------------------------------------------
__global__ __launch_bounds__(256) void fill_kernel(const int* __restrict__ src,
                                                   const int* __restrict__ dst,
                                                   const float* __restrict__ edge_w,
                                                   const int* __restrict__ rank,
                                                   const int* __restrict__ offsets,
                                                   int2* __restrict__ ep) {
    int base = (blockIdx.x * 256 + threadIdx.x) * 4;
    if (base >= N_EDGES) return;
    int4   s4 = *(const int4*)&src[base];
    int4   d4 = *(const int4*)&dst[base];
    int4   r4 = *(const int4*)&rank[base];
    float4 w4 = *(const float4*)&edge_w[base];
    ep[offsets[d4.x] + r4.x] = make_int2(s4.x, __float_as_int(w4.x));
    ep[offsets[d4.y] + r4.y] = make_int2(s4.y, __float_as_int(w4.y));
    ep[offsets[d4.z] + r4.z] = make_int2(s4.z, __float_as_int(w4.z));
    ep[offsets[d4.w] + r4.w] = make_int2(s4.w, __float_as_int(w4.w));
}

// ---------------------------------------------------------------------------
// Gather: out[i] = b + sum w_e * h_bf16[src_e]. 16 lanes/node, unroll 4,
// register accumulation. Unchanged (proven).
// ---------------------------------------------------------------------------
__global__ __launch_bounds__(256) void gather_kernel(const unsigned short* __restrict__ h,
                                                     const int2* __restrict__ ep,
                                                     const int* __restrict__ offsets,
                                                     const float* __restrict__ b,
                                                     float* __restrict__ out) {
    int t    = blockIdx.x * blockDim.x + threadIdx.x;
    int node = t >> 4;
    int lane = t & 15;
    if (node >= M_NODES) return;
    int beg = offsets[node];
    int end = offsets[node + 1];

    float4 b0 = *(const float4*)&b[lane * 8];
    float4 b1 = *(const float4*)&b[lane * 8 + 4];
    float a[4][8];
#pragma unroll
    for (int u = 0; u < 4; ++u)
#pragma unroll
        for (int c = 0; c < 8; ++c) a[u][c] = 0.f;

    int j = beg;
    for (; j + 4 <= end; j += 4) {
        int2 e0 = ep[j], e1 = ep[j + 1], e2 = ep[j + 2], e3 = ep[j + 3];
        uint4 q0 = *(const uint4*)(h + (size_t)e0.x * D_OUT_N + lane * 8);
        uint4 q1 = *(const uint4*)(h + (size_t)e1.x * D_OUT_N + lane * 8);
        uint4 q2 = *(const uint4*)(h + (size_t)e2.x * D_OUT_N + lane * 8);
        uint4 q3 = *(const uint4*)(h + (size_t)e3.x * D_OUT_N + lane * 8);
        float w0 = __int_as_float(e0.y), w1 = __int_as_float(e1.y);
        float w2 = __int_as_float(e2.y), w3 = __int_as_float(e3.y);
        a[0][0] += w0 * bflo(q0.x);  a[0][1] += w0 * bfhi(q0.x);
        a[0][2] += w0 * bflo(q0.y);  a[0][3] += w0 * bfhi(q0.y);
        a[0][4] += w0 * bflo(q0.z);  a[0][5] += w0 * bfhi(q0.z);
        a[0][6] += w0 * bflo(q0.w);  a[0][7] += w0 * bfhi(q0.w);
        a[1][0] += w1 * bflo(q1.x);  a[1][1] += w1 * bfhi(q1.x);
        a[1][2] += w1 * bflo(q1.y);  a[1][3] += w1 * bfhi(q1.y);
        a[1][4] += w1 * bflo(q1.z);  a[1][5] += w1 * bfhi(q1.z);
        a[1][6] += w1 * bflo(q1.w);  a[1][7] += w1 * bfhi(q1.w);
        a[2][0] += w2 * bflo(q2.x);  a[2][1] += w2 * bfhi(q2.x);
        a[2][2] += w2 * bflo(q2.y);  a[2][3] += w2 * bfhi(q2.y);
        a[2][4] += w2 * bflo(q2.z);  a[2][5] += w2 * bfhi(q2.z);
        a[2][6] += w2 * bflo(q2.w);  a[2][7] += w2 * bfhi(q2.w);
        a[3][0] += w3 * bflo(q3.x);  a[3][1] += w3 * bfhi(q3.x);
        a[3][2] += w3 * bflo(q3.y);  a[3][3] += w3 * bfhi(q3.y);
        a[3][4] += w3 * bflo(q3.z);  a[3][5] += w3 * bfhi(q3.z);
        a[3][6] += w3 * bflo(q3.w);  a[3][7] += w3 * bfhi(q3.w);
    }
    for (; j < end; ++j) {
        int2 e0 = ep[j];
        float w0 = __int_as_float(e0.y);
        uint4 q0 = *(const uint4*)(h + (size_t)e0.x * D_OUT_N + lane * 8);
        a[0][0] += w0 * bflo(q0.x);  a[0][1] += w0 * bfhi(q0.x);
        a[0][2] += w0 * bflo(q0.y);  a[0][3] += w0 * bfhi(q0.y);
        a[0][4] += w0 * bflo(q0.z);  a[0][5] += w0 * bfhi(q0.z);
        a[0][6] += w0 * bflo(q0.w);  a[0][7] += w0 * bfhi(q0.w);
    }

    float4 o0 = make_float4(b0.x + a[0][0] + a[1][0] + a[2][0] + a[3][0],
                            b0.y + a[0][1] + a[1][1] + a[2][1] + a[3][1],
                            b0.z + a[0][2] + a[1][2] + a[2][2] + a[3][2],
                            b0.w + a[0][3] + a[1][3] + a[2][3] + a[3][3]);
    float4 o1 = make_float4(b1.x + a[0][4] + a[1][4] + a[2][4] + a[3][4],
                            b1.y + a[0][5] + a[1][5] + a[2][5] + a[3][5],
                            b1.z + a[0][6] + a[1][6] + a[2][6] + a[3][6],
                            b1.w + a[0][7] + a[1][7] + a[2][7] + a[3][7]);
    float* op = &out[(size_t)node * D_OUT_N + lane * 8];
    *(float4*)op = o0;
    *(float4*)(op + 4) = o1;
}

extern "C" void kernel_launch(void* const* d_in, const int* in_sizes, int n_in,
                              void* d_out, int out_size, void* d_ws, size_t ws_size,
                              hipStream_t stream) {
    const float* x      = (const float*)d_in[0];
    const float* edge_w = (const float*)d_in[1];
    const int*   src    = (const int*)d_in[2];
    const int*   dst    = (const int*)d_in[3];
    const float* W      = (const float*)d_in[4];
    const float* b      = (const float*)d_in[5];
    float* out = (float*)d_out;

    char* wsp = (char*)d_ws;
    unsigned short* h = (unsigned short*)wsp;  wsp += (size_t)M_NODES * D_OUT_N * 2;      // 12.8 MB
    int*   counts   = (int*)wsp;         wsp += (size_t)M_NODES * 4;                      // 200 KB
    int*   flags    = (int*)wsp;         wsp += 64 * 4;                                   // 256 B (zeroed w/ counts)
    int*   offsets  = (int*)wsp;         wsp += (((size_t)M_NODES + 1) * 4 + 15) & ~15ull;
    int*   rank     = (int*)wsp;         wsp += (size_t)N_EDGES * 4;                      // 3.2 MB
    int2*  ep       = (int2*)wsp;        wsp += (size_t)N_EDGES * 8;                      // 6.4 MB
    unsigned short* Wp = (unsigned short*)wsp; wsp += (size_t)16 * 8 * 64 * 8 * 2;        // 128 KB
    int*   partials = (int*)wsp;         wsp += (SCAN_NBLK * 4 + 15) & ~15ull;

    permw_kernel<<<32, 256, 0, stream>>>(W, Wp, counts);   // also zeroes counts+flags
    mfma_gemm_hist_kernel<<<(M_NODES + 127) / 128, 512, 0, stream>>>(
        x, (const uint4*)Wp, h, dst, counts, rank);
    scan_kernel<<<SCAN_NBLK, 256, 0, stream>>>(counts, offsets, partials, flags);
    fill_kernel<<<(N_EDGES / 4 + 255) / 256, 256, 0, stream>>>(src, dst, edge_w, rank, offsets, ep);
    gather_kernel<<<(int)(((long long)M_NODES * 16 + 255) / 256), 256, 0, stream>>>(
        h, ep, offsets, b, out);
}

// Round 12
// 252.986 us; speedup vs baseline: 1.0226x; 1.0226x over previous
//
#include <hip/hip_runtime.h>
#include <hip/hip_bf16.h>

#define M_NODES  50000
#define D_IN_K   512
#define D_OUT_N  128
#define N_EDGES  800000
#define SCAN_NBLK 49   // ceil(50000/1024)

typedef short  bf16x8 __attribute__((ext_vector_type(8)));
typedef float  f32x4  __attribute__((ext_vector_type(4)));

static __device__ __forceinline__ unsigned short f2bf(float f) {
    unsigned u = __float_as_uint(f);
    unsigned r = u + 0x7FFF + ((u >> 16) & 1);   // RNE
    return (unsigned short)(r >> 16);
}
static __device__ __forceinline__ float bflo(unsigned q) { return __uint_as_float(q << 16); }
static __device__ __forceinline__ float bfhi(unsigned q) { return __uint_as_float(q & 0xFFFF0000u); }

// async global->LDS 16B (wave-uniform LDS base + lane*16: linear tid indexing)
static __device__ __forceinline__ void gl2lds16(const uint4* g, uint4* l) {
    __builtin_amdgcn_global_load_lds(
        (const __attribute__((address_space(1))) void*)g,
        (__attribute__((address_space(3))) void*)l,
        16, 0, 0);
}

// ---------------------------------------------------------------------------
// Permute W (fp32 [512][128]) into bf16 B-fragment order (uint4 frags).
// Also zeroes counts+flags (50064 ints) -> no memset dispatch.
// ---------------------------------------------------------------------------
__global__ __launch_bounds__(256) void permw_kernel(const float* __restrict__ W,
                                                    unsigned short* __restrict__ Wp,
                                                    int* __restrict__ counts) {
    int tid = blockIdx.x * 256 + threadIdx.x;  // 0..8191
    int lane = tid & 63;
    int nt   = (tid >> 6) & 7;
    int kb4  = tid >> 9;
    int n    = nt * 16 + (lane & 15);
    int kbase = kb4 * 32 + ((lane >> 4) & 3) * 8;
    unsigned short frag[8];
#pragma unroll
    for (int j = 0; j < 8; ++j)
        frag[j] = f2bf(W[(size_t)(kbase + j) * D_OUT_N + n]);
    *(uint4*)&Wp[(size_t)tid * 8] = *(const uint4*)frag;

    // zero counts (50000) + flags (64), contiguous in workspace
    for (int i = tid; i < M_NODES + 64; i += 8192) counts[i] = 0;
}

// ---------------------------------------------------------------------------
// h(bf16) = x @ W, 512 threads (8 waves x 16 rows). NEW: full-half x
// prefetch — all 16 float4 loads for the half issued back-to-back (MLP=16),
// drained once by the staging barrier, kb-loop then runs from registers.
// W staged via global_load_lds (zero staging VGPRs -> ax[16] fits under the
// 128-VGPR cap). Tail: fused histogram+rank (throughput-bound ~17-19us,
// placement-insensitive per r4/r11).
// ---------------------------------------------------------------------------
__global__ __launch_bounds__(512, 4) void mfma_gemm_hist_kernel(const float* __restrict__ x,
                                                                const uint4* __restrict__ Wp4,
                                                                unsigned short* __restrict__ h,
                                                                const int* __restrict__ dst,
                                                                int* __restrict__ counts,
                                                                int* __restrict__ rank) {
    __shared__ uint4 wlds[4096];              // 64 KB: [kb 8][nt 8][lane 64]

    const int tid  = threadIdx.x;
    const int wave = tid >> 6;                // 0..7
    const int lane = tid & 63;
    const int m0   = blockIdx.x * 128 + wave * 16;
    const int mrow = lane & 15;
    const int kgrp = lane >> 4;               // 0..3

    const int r0 = m0 + mrow;
    const float* xr0 = x + (size_t)((r0 < M_NODES) ? r0 : M_NODES - 1) * D_IN_K + kgrp * 8;

    f32x4 acc[8];
#pragma unroll
    for (int t = 0; t < 8; ++t) acc[t] = (f32x4){0.f, 0.f, 0.f, 0.f};

    for (int half = 0; half < 2; ++half) {
        __syncthreads();                      // prior half's wlds reads done
        // W staging: async global->LDS, no VGPR round-trip
#pragma unroll
        for (int i = 0; i < 8; ++i)
            gl2lds16(Wp4 + half * 4096 + tid + i * 512, &wlds[tid + i * 512]);

        // full-half x prefetch: 16 independent loads in flight
        const float* px0 = xr0 + half * 256;
        float4 ax[16];
#pragma unroll
        for (int kb = 0; kb < 8; ++kb) {
            ax[2 * kb]     = *(const float4*)(px0 + kb * 32);
            ax[2 * kb + 1] = *(const float4*)(px0 + kb * 32 + 4);
        }

        __syncthreads();                      // vmcnt(0): W in LDS, ax in regs

#pragma unroll
        for (int kb = 0; kb < 8; ++kb) {
            union { bf16x8 v; __hip_bfloat162 h2[4]; } c0;
            c0.h2[0] = __float22bfloat162_rn(make_float2(ax[2 * kb].x, ax[2 * kb].y));
            c0.h2[1] = __float22bfloat162_rn(make_float2(ax[2 * kb].z, ax[2 * kb].w));
            c0.h2[2] = __float22bfloat162_rn(make_float2(ax[2 * kb + 1].x, ax[2 * kb + 1].y));
            c0.h2[3] = __float22bfloat162_rn(make_float2(ax[2 * kb + 1].z, ax[2 * kb + 1].w));
            bf16x8 a0 = c0.v;

#pragma unroll
            for (int nt = 0; nt < 8; ++nt) {
                union { uint4 u; bf16x8 v; } wb;
                wb.u = wlds[(kb * 8 + nt) * 64 + lane];
                acc[nt] = __builtin_amdgcn_mfma_f32_16x16x32_bf16(a0, wb.v, acc[nt], 0, 0, 0);
            }
        }
    }

    // epilogue: C/D layout col=lane&15, row=kgrp*4+r
#pragma unroll
    for (int r = 0; r < 4; ++r) {
        int rr = m0 + kgrp * 4 + r;
        if (rr < M_NODES) {
            unsigned short* hp = h + (size_t)rr * D_OUT_N + mrow;
#pragma unroll
            for (int nt = 0; nt < 8; ++nt)
                hp[nt * 16] = f2bf(acc[nt][r]);
        }
    }

    // --- fused histogram tail: atomic return value IS the edge's rank ---
    const int epb = (N_EDGES + gridDim.x - 1) / gridDim.x;   // 2047
    const int e0  = blockIdx.x * epb;
    const int e1  = (e0 + epb < N_EDGES) ? e0 + epb : N_EDGES;
    for (int e = e0 + tid; e < e1; e += 512)
        rank[e] = atomicAdd(&counts[dst[e]], 1);
}

// ---------------------------------------------------------------------------
// Single-launch exclusive scan (49 co-resident blocks, lookback on flags).
// ---------------------------------------------------------------------------
__global__ __launch_bounds__(256) void scan_kernel(const int* __restrict__ counts,
                                                   int* __restrict__ offsets,
                                                   int* __restrict__ partials,
                                                   int* __restrict__ flags) {
    __shared__ int wsum[4];
    __shared__ int carry_s;
    const int tid  = threadIdx.x;
    const int lane = tid & 63;
    const int wid  = tid >> 6;
    const int blk  = blockIdx.x;
    const int base = blk * 1024 + tid * 4;

    int v[4];
    if (base + 3 < M_NODES) {
        int4 q = *(const int4*)&counts[base];
        v[0] = q.x; v[1] = q.y; v[2] = q.z; v[3] = q.w;
    } else {
#pragma unroll
        for (int i = 0; i < 4; ++i)
            v[i] = (base + i < M_NODES) ? counts[base + i] : 0;
    }
    int t = v[0] + v[1] + v[2] + v[3];

    int s = t;
#pragma unroll
    for (int d = 1; d < 64; d <<= 1) {
        int u = __shfl_up(s, d, 64);
        if (lane >= d) s += u;
    }
    if (lane == 63) wsum[wid] = s;
    __syncthreads();
    int wbase = 0;
#pragma unroll
    for (int w = 0; w < 4; ++w) wbase += (w < wid) ? wsum[w] : 0;
    int total = wsum[0] + wsum[1] + wsum[2] + wsum[3];

    if (tid == 0) {
        __hip_atomic_store(&partials[blk], total, __ATOMIC_RELAXED, __HIP_MEMORY_SCOPE_AGENT);
        __hip_atomic_store(&flags[blk], 1, __ATOMIC_RELEASE, __HIP_MEMORY_SCOPE_AGENT);
        if (blk == 0) offsets[M_NODES] = N_EDGES;
    }

    if (wid == 0) {
        int val = 0;
        if (lane < blk) {
            while (__hip_atomic_load(&flags[lane], __ATOMIC_ACQUIRE, __HIP_MEMORY_SCOPE_AGENT) == 0) {}
            val = __hip_atomic_load(&partials[lane], __ATOMIC_RELAXED, __HIP_MEMORY_SCOPE_AGENT);
        }
#pragma unroll
        for (int d = 32; d > 0; d >>= 1) val += __shfl_xor(val, d, 64);
        if (lane == 0) carry_s = val;
    }
    __syncthreads();
    const int carry = carry_s;

    int run = carry + wbase + s - t;   // exclusive prefix for this thread's 4 nodes
#pragma unroll
    for (int i = 0; i < 4; ++i) {
        if (base + i < M_NODES) offsets[base + i] = run;
        run += v[i];
    }
}

// ---------------------------------------------------------------------------
// Permute edges into CSR order — ATOMIC-FREE: pos = offsets[dst] + rank.
// ---------------------------------------------------------------------------
__global__ __launch_bounds__(256) void fill_kernel(const int* __restrict__ src,
                                                   const int* __restrict__ dst,
                                                   const float* __restrict__ edge_w,
                                                   const int* __restrict__ rank,
                                                   const int* __restrict__ offsets,
                                                   int2* __restrict__ ep) {
    int base = (blockIdx.x * 256 + threadIdx.x) * 4;
    if (base >= N_EDGES) return;
    int4   s4 = *(const int4*)&src[base];
    int4   d4 = *(const int4*)&dst[base];
    int4   r4 = *(const int4*)&rank[base];
    float4 w4 = *(const float4*)&edge_w[base];
    ep[offsets[d4.x] + r4.x] = make_int2(s4.x, __float_as_int(w4.x));
    ep[offsets[d4.y] + r4.y] = make_int2(s4.y, __float_as_int(w4.y));
    ep[offsets[d4.z] + r4.z] = make_int2(s4.z, __float_as_int(w4.z));
    ep[offsets[d4.w] + r4.w] = make_int2(s4.w, __float_as_int(w4.w));
}

// ---------------------------------------------------------------------------
// Gather: out[i] = b + sum w_e * h_bf16[src_e]. 16 lanes/node, unroll 4,
// register accumulation. Unchanged (proven).
// ---------------------------------------------------------------------------
__global__ __launch_bounds__(256) void gather_kernel(const unsigned short* __restrict__ h,
                                                     const int2* __restrict__ ep,
                                                     const int* __restrict__ offsets,
                                                     const float* __restrict__ b,
                                                     float* __restrict__ out) {
    int t    = blockIdx.x * blockDim.x + threadIdx.x;
    int node = t >> 4;
    int lane = t & 15;
    if (node >= M_NODES) return;
    int beg = offsets[node];
    int end = offsets[node + 1];

    float4 b0 = *(const float4*)&b[lane * 8];
    float4 b1 = *(const float4*)&b[lane * 8 + 4];
    float a[4][8];
#pragma unroll
    for (int u = 0; u < 4; ++u)
#pragma unroll
        for (int c = 0; c < 8; ++c) a[u][c] = 0.f;

    int j = beg;
    for (; j + 4 <= end; j += 4) {
        int2 e0 = ep[j], e1 = ep[j + 1], e2 = ep[j + 2], e3 = ep[j + 3];
        uint4 q0 = *(const uint4*)(h + (size_t)e0.x * D_OUT_N + lane * 8);
        uint4 q1 = *(const uint4*)(h + (size_t)e1.x * D_OUT_N + lane * 8);
        uint4 q2 = *(const uint4*)(h + (size_t)e2.x * D_OUT_N + lane * 8);
        uint4 q3 = *(const uint4*)(h + (size_t)e3.x * D_OUT_N + lane * 8);
        float w0 = __int_as_float(e0.y), w1 = __int_as_float(e1.y);
        float w2 = __int_as_float(e2.y), w3 = __int_as_float(e3.y);
        a[0][0] += w0 * bflo(q0.x);  a[0][1] += w0 * bfhi(q0.x);
        a[0][2] += w0 * bflo(q0.y);  a[0][3] += w0 * bfhi(q0.y);
        a[0][4] += w0 * bflo(q0.z);  a[0][5] += w0 * bfhi(q0.z);
        a[0][6] += w0 * bflo(q0.w);  a[0][7] += w0 * bfhi(q0.w);
        a[1][0] += w1 * bflo(q1.x);  a[1][1] += w1 * bfhi(q1.x);
        a[1][2] += w1 * bflo(q1.y);  a[1][3] += w1 * bfhi(q1.y);
        a[1][4] += w1 * bflo(q1.z);  a[1][5] += w1 * bfhi(q1.z);
        a[1][6] += w1 * bflo(q1.w);  a[1][7] += w1 * bfhi(q1.w);
        a[2][0] += w2 * bflo(q2.x);  a[2][1] += w2 * bfhi(q2.x);
        a[2][2] += w2 * bflo(q2.y);  a[2][3] += w2 * bfhi(q2.y);
        a[2][4] += w2 * bflo(q2.z);  a[2][5] += w2 * bfhi(q2.z);
        a[2][6] += w2 * bflo(q2.w);  a[2][7] += w2 * bfhi(q2.w);
        a[3][0] += w3 * bflo(q3.x);  a[3][1] += w3 * bfhi(q3.x);
        a[3][2] += w3 * bflo(q3.y);  a[3][3] += w3 * bfhi(q3.y);
        a[3][4] += w3 * bflo(q3.z);  a[3][5] += w3 * bfhi(q3.z);
        a[3][6] += w3 * bflo(q3.w);  a[3][7] += w3 * bfhi(q3.w);
    }
    for (; j < end; ++j) {
        int2 e0 = ep[j];
        float w0 = __int_as_float(e0.y);
        uint4 q0 = *(const uint4*)(h + (size_t)e0.x * D_OUT_N + lane * 8);
        a[0][0] += w0 * bflo(q0.x);  a[0][1] += w0 * bfhi(q0.x);
        a[0][2] += w0 * bflo(q0.y);  a[0][3] += w0 * bfhi(q0.y);
        a[0][4] += w0 * bflo(q0.z);  a[0][5] += w0 * bfhi(q0.z);
        a[0][6] += w0 * bflo(q0.w);  a[0][7] += w0 * bfhi(q0.w);
    }

    float4 o0 = make_float4(b0.x + a[0][0] + a[1][0] + a[2][0] + a[3][0],
                            b0.y + a[0][1] + a[1][1] + a[2][1] + a[3][1],
                            b0.z + a[0][2] + a[1][2] + a[2][2] + a[3][2],
                            b0.w + a[0][3] + a[1][3] + a[2][3] + a[3][3]);
    float4 o1 = make_float4(b1.x + a[0][4] + a[1][4] + a[2][4] + a[3][4],
                            b1.y + a[0][5] + a[1][5] + a[2][5] + a[3][5],
                            b1.z + a[0][6] + a[1][6] + a[2][6] + a[3][6],
                            b1.w + a[0][7] + a[1][7] + a[2][7] + a[3][7]);
    float* op = &out[(size_t)node * D_OUT_N + lane * 8];
    *(float4*)op = o0;
    *(float4*)(op + 4) = o1;
}

extern "C" void kernel_launch(void* const* d_in, const int* in_sizes, int n_in,
                              void* d_out, int out_size, void* d_ws, size_t ws_size,
                              hipStream_t stream) {
    const float* x      = (const float*)d_in[0];
    const float* edge_w = (const float*)d_in[1];
    const int*   src    = (const int*)d_in[2];
    const int*   dst    = (const int*)d_in[3];
    const float* W      = (const float*)d_in[4];
    const float* b      = (const float*)d_in[5];
    float* out = (float*)d_out;

    char* wsp = (char*)d_ws;
    unsigned short* h = (unsigned short*)wsp;  wsp += (size_t)M_NODES * D_OUT_N * 2;      // 12.8 MB
    int*   counts   = (int*)wsp;         wsp += (size_t)M_NODES * 4;                      // 200 KB
    int*   flags    = (int*)wsp;         wsp += 64 * 4;                                   // 256 B (zeroed w/ counts)
    int*   offsets  = (int*)wsp;         wsp += (((size_t)M_NODES + 1) * 4 + 15) & ~15ull;
    int*   rank     = (int*)wsp;         wsp += (size_t)N_EDGES * 4;                      // 3.2 MB
    int2*  ep       = (int2*)wsp;        wsp += (size_t)N_EDGES * 8;                      // 6.4 MB
    unsigned short* Wp = (unsigned short*)wsp; wsp += (size_t)16 * 8 * 64 * 8 * 2;        // 128 KB
    int*   partials = (int*)wsp;         wsp += (SCAN_NBLK * 4 + 15) & ~15ull;

    permw_kernel<<<32, 256, 0, stream>>>(W, Wp, counts);   // also zeroes counts+flags
    mfma_gemm_hist_kernel<<<(M_NODES + 127) / 128, 512, 0, stream>>>(
        x, (const uint4*)Wp, h, dst, counts, rank);
    scan_kernel<<<SCAN_NBLK, 256, 0, stream>>>(counts, offsets, partials, flags);
    fill_kernel<<<(N_EDGES / 4 + 255) / 256, 256, 0, stream>>>(src, dst, edge_w, rank, offsets, ep);
    gather_kernel<<<(int)(((long long)M_NODES * 16 + 255) / 256), 256, 0, stream>>>(
        h, ep, offsets, b, out);
}

// Round 13
// 249.413 us; speedup vs baseline: 1.0373x; 1.0143x over previous
//
#include <hip/hip_runtime.h>
#include <hip/hip_bf16.h>

#define M_NODES  50000
#define D_IN_K   512
#define D_OUT_N  128
#define N_EDGES  800000
#define SCAN_NBLK 49   // ceil(50000/1024)

typedef short  bf16x8 __attribute__((ext_vector_type(8)));
typedef float  f32x4  __attribute__((ext_vector_type(4)));

static __device__ __forceinline__ unsigned short f2bf(float f) {
    unsigned u = __float_as_uint(f);
    unsigned r = u + 0x7FFF + ((u >> 16) & 1);   // RNE
    return (unsigned short)(r >> 16);
}
static __device__ __forceinline__ float bflo(unsigned q) { return __uint_as_float(q << 16); }
static __device__ __forceinline__ float bfhi(unsigned q) { return __uint_as_float(q & 0xFFFF0000u); }

// async global->LDS 16B (wave-uniform LDS base + lane*16: linear tid indexing)
static __device__ __forceinline__ void gl2lds16(const uint4* g, uint4* l) {
    __builtin_amdgcn_global_load_lds(
        (const __attribute__((address_space(1))) void*)g,
        (__attribute__((address_space(3))) void*)l,
        16, 0, 0);
}

// ---------------------------------------------------------------------------
// Permute W (fp32 [512][128]) into bf16 B-fragment order (uint4 frags).
// Also zeroes counts+flags (50064 ints) -> no memset dispatch.
// ---------------------------------------------------------------------------
__global__ __launch_bounds__(256) void permw_kernel(const float* __restrict__ W,
                                                    unsigned short* __restrict__ Wp,
                                                    int* __restrict__ counts) {
    int tid = blockIdx.x * 256 + threadIdx.x;  // 0..8191
    int lane = tid & 63;
    int nt   = (tid >> 6) & 7;
    int kb4  = tid >> 9;
    int n    = nt * 16 + (lane & 15);
    int kbase = kb4 * 32 + ((lane >> 4) & 3) * 8;
    unsigned short frag[8];
#pragma unroll
    for (int j = 0; j < 8; ++j)
        frag[j] = f2bf(W[(size_t)(kbase + j) * D_OUT_N + n]);
    *(uint4*)&Wp[(size_t)tid * 8] = *(const uint4*)frag;

    // zero counts (50000) + flags (64), contiguous in workspace
    for (int i = tid; i < M_NODES + 64; i += 8192) counts[i] = 0;
}

// ---------------------------------------------------------------------------
// h(bf16) = x @ W, 512 threads (8 waves x 16 rows), MLP=16 x prefetch (r12
// proven). NEW: histogram atomics overlapped with half-1 compute via T4
// counted-vmcnt: atomics issued NEWEST (after staging+x), then
// s_waitcnt vmcnt(4) (drains staging+x, keeps 4 atomics in flight) + raw
// s_barrier. Ranks consumed only at the epilogue -> the 800k-atomic drain
// (~17us chip-wide) hides under the half-1 MFMA loop instead of extending
// the kernel. (r11's entry-issue failed because __syncthreads' vmcnt(0)
// drained the atomics before GEMM start — vmcnt retires oldest-first.)
// ---------------------------------------------------------------------------
__global__ __launch_bounds__(512, 4) void mfma_gemm_hist_kernel(const float* __restrict__ x,
                                                                const uint4* __restrict__ Wp4,
                                                                unsigned short* __restrict__ h,
                                                                const int* __restrict__ dst,
                                                                int* __restrict__ counts,
                                                                int* __restrict__ rank) {
    __shared__ uint4 wlds[4096];              // 64 KB: [kb 8][nt 8][lane 64]

    const int tid  = threadIdx.x;
    const int wave = tid >> 6;                // 0..7
    const int lane = tid & 63;
    const int m0   = blockIdx.x * 128 + wave * 16;
    const int mrow = lane & 15;
    const int kgrp = lane >> 4;               // 0..3

    // dst quad loaded early (independent); atomics issued in half 1
    const int ebase = (blockIdx.x * 512 + tid) * 4;   // 391*512*4 >= 800000
    const bool edo = ebase < N_EDGES;                 // N_EDGES%4==0 -> full quad
    int4 d4 = make_int4(0, 0, 0, 0);
    if (edo) d4 = *(const int4*)&dst[ebase];

    const int r0 = m0 + mrow;
    const float* xr0 = x + (size_t)((r0 < M_NODES) ? r0 : M_NODES - 1) * D_IN_K + kgrp * 8;

    f32x4 acc[8];
#pragma unroll
    for (int t = 0; t < 8; ++t) acc[t] = (f32x4){0.f, 0.f, 0.f, 0.f};

    float4 ax[16];

    // ================= half 0 =================
#pragma unroll
    for (int i = 0; i < 8; ++i)
        gl2lds16(Wp4 + tid + i * 512, &wlds[tid + i * 512]);
#pragma unroll
    for (int kb = 0; kb < 8; ++kb) {
        ax[2 * kb]     = *(const float4*)(xr0 + kb * 32);
        ax[2 * kb + 1] = *(const float4*)(xr0 + kb * 32 + 4);
    }
    __syncthreads();                          // vmcnt(0): W staged, ax in regs

#pragma unroll
    for (int kb = 0; kb < 8; ++kb) {
        union { bf16x8 v; __hip_bfloat162 h2[4]; } c0;
        c0.h2[0] = __float22bfloat162_rn(make_float2(ax[2 * kb].x, ax[2 * kb].y));
        c0.h2[1] = __float22bfloat162_rn(make_float2(ax[2 * kb].z, ax[2 * kb].w));
        c0.h2[2] = __float22bfloat162_rn(make_float2(ax[2 * kb + 1].x, ax[2 * kb + 1].y));
        c0.h2[3] = __float22bfloat162_rn(make_float2(ax[2 * kb + 1].z, ax[2 * kb + 1].w));
        bf16x8 a0 = c0.v;
#pragma unroll
        for (int nt = 0; nt < 8; ++nt) {
            union { uint4 u; bf16x8 v; } wb;
            wb.u = wlds[(kb * 8 + nt) * 64 + lane];
            acc[nt] = __builtin_amdgcn_mfma_f32_16x16x32_bf16(a0, wb.v, acc[nt], 0, 0, 0);
        }
    }

    // ================= half 1 =================
    __syncthreads();                          // all half-0 wlds reads done
#pragma unroll
    for (int i = 0; i < 8; ++i)
        gl2lds16(Wp4 + 4096 + tid + i * 512, &wlds[tid + i * 512]);
    const float* px1 = xr0 + 256;
#pragma unroll
    for (int kb = 0; kb < 8; ++kb) {
        ax[2 * kb]     = *(const float4*)(px1 + kb * 32);
        ax[2 * kb + 1] = *(const float4*)(px1 + kb * 32 + 4);
    }
    // atomics issued LAST (newest outstanding vmem ops)
    int4 r4 = make_int4(0, 0, 0, 0);
    if (edo) {
        r4.x = atomicAdd(&counts[d4.x], 1);
        r4.y = atomicAdd(&counts[d4.y], 1);
        r4.z = atomicAdd(&counts[d4.z], 1);
        r4.w = atomicAdd(&counts[d4.w], 1);
    }
    // counted wait: drains staging+x (oldest 24), leaves 4 atomics in flight
    asm volatile("s_waitcnt vmcnt(4)" ::: "memory");
    __builtin_amdgcn_sched_barrier(0);
    __builtin_amdgcn_s_barrier();

#pragma unroll
    for (int kb = 0; kb < 8; ++kb) {
        union { bf16x8 v; __hip_bfloat162 h2[4]; } c0;
        c0.h2[0] = __float22bfloat162_rn(make_float2(ax[2 * kb].x, ax[2 * kb].y));
        c0.h2[1] = __float22bfloat162_rn(make_float2(ax[2 * kb].z, ax[2 * kb].w));
        c0.h2[2] = __float22bfloat162_rn(make_float2(ax[2 * kb + 1].x, ax[2 * kb + 1].y));
        c0.h2[3] = __float22bfloat162_rn(make_float2(ax[2 * kb + 1].z, ax[2 * kb + 1].w));
        bf16x8 a0 = c0.v;
#pragma unroll
        for (int nt = 0; nt < 8; ++nt) {
            union { uint4 u; bf16x8 v; } wb;
            wb.u = wlds[(kb * 8 + nt) * 64 + lane];
            acc[nt] = __builtin_amdgcn_mfma_f32_16x16x32_bf16(a0, wb.v, acc[nt], 0, 0, 0);
        }
    }

    // epilogue: C/D layout col=lane&15, row=kgrp*4+r
#pragma unroll
    for (int r = 0; r < 4; ++r) {
        int rr = m0 + kgrp * 4 + r;
        if (rr < M_NODES) {
            unsigned short* hp = h + (size_t)rr * D_OUT_N + mrow;
#pragma unroll
            for (int nt = 0; nt < 8; ++nt)
                hp[nt * 16] = f2bf(acc[nt][r]);
        }
    }

    // rank store: first (and only) consumer of the atomic returns
    if (edo) *(int4*)&rank[ebase] = r4;
}

// ---------------------------------------------------------------------------
// Single-launch exclusive scan (49 co-resident blocks, lookback on flags).
// ---------------------------------------------------------------------------
__global__ __launch_bounds__(256) void scan_kernel(const int* __restrict__ counts,
                                                   int* __restrict__ offsets,
                                                   int* __restrict__ partials,
                                                   int* __restrict__ flags) {
    __shared__ int wsum[4];
    __shared__ int carry_s;
    const int tid  = threadIdx.x;
    const int lane = tid & 63;
    const int wid  = tid >> 6;
    const int blk  = blockIdx.x;
    const int base = blk * 1024 + tid * 4;

    int v[4];
    if (base + 3 < M_NODES) {
        int4 q = *(const int4*)&counts[base];
        v[0] = q.x; v[1] = q.y; v[2] = q.z; v[3] = q.w;
    } else {
#pragma unroll
        for (int i = 0; i < 4; ++i)
            v[i] = (base + i < M_NODES) ? counts[base + i] : 0;
    }
    int t = v[0] + v[1] + v[2] + v[3];

    int s = t;
#pragma unroll
    for (int d = 1; d < 64; d <<= 1) {
        int u = __shfl_up(s, d, 64);
        if (lane >= d) s += u;
    }
    if (lane == 63) wsum[wid] = s;
    __syncthreads();
    int wbase = 0;
#pragma unroll
    for (int w = 0; w < 4; ++w) wbase += (w < wid) ? wsum[w] : 0;
    int total = wsum[0] + wsum[1] + wsum[2] + wsum[3];

    if (tid == 0) {
        __hip_atomic_store(&partials[blk], total, __ATOMIC_RELAXED, __HIP_MEMORY_SCOPE_AGENT);
        __hip_atomic_store(&flags[blk], 1, __ATOMIC_RELEASE, __HIP_MEMORY_SCOPE_AGENT);
        if (blk == 0) offsets[M_NODES] = N_EDGES;
    }

    if (wid == 0) {
        int val = 0;
        if (lane < blk) {
            while (__hip_atomic_load(&flags[lane], __ATOMIC_ACQUIRE, __HIP_MEMORY_SCOPE_AGENT) == 0) {}
            val = __hip_atomic_load(&partials[lane], __ATOMIC_RELAXED, __HIP_MEMORY_SCOPE_AGENT);
        }
#pragma unroll
        for (int d = 32; d > 0; d >>= 1) val += __shfl_xor(val, d, 64);
        if (lane == 0) carry_s = val;
    }
    __syncthreads();
    const int carry = carry_s;

    int run = carry + wbase + s - t;   // exclusive prefix for this thread's 4 nodes
#pragma unroll
    for (int i = 0; i < 4; ++i) {
        if (base + i < M_NODES) offsets[base + i] = run;
        run += v[i];
    }
}

// ---------------------------------------------------------------------------
// Permute edges into CSR order — ATOMIC-FREE: pos = offsets[dst] + rank.
// ---------------------------------------------------------------------------
__global__ __launch_bounds__(256) void fill_kernel(const int* __restrict__ src,
                                                   const int* __restrict__ dst,
                                                   const float* __restrict__ edge_w,
                                                   const int* __restrict__ rank,
                                                   const int* __restrict__ offsets,
                                                   int2* __restrict__ ep) {
    int base = (blockIdx.x * 256 + threadIdx.x) * 4;
    if (base >= N_EDGES) return;
    int4   s4 = *(const int4*)&src[base];
    int4   d4 = *(const int4*)&dst[base];
    int4   r4 = *(const int4*)&rank[base];
    float4 w4 = *(const float4*)&edge_w[base];
    ep[offsets[d4.x] + r4.x] = make_int2(s4.x, __float_as_int(w4.x));
    ep[offsets[d4.y] + r4.y] = make_int2(s4.y, __float_as_int(w4.y));
    ep[offsets[d4.z] + r4.z] = make_int2(s4.z, __float_as_int(w4.z));
    ep[offsets[d4.w] + r4.w] = make_int2(s4.w, __float_as_int(w4.w));
}

// ---------------------------------------------------------------------------
// Gather: out[i] = b + sum w_e * h_bf16[src_e]. 16 lanes/node, unroll 4,
// register accumulation. Unchanged (proven).
// ---------------------------------------------------------------------------
__global__ __launch_bounds__(256) void gather_kernel(const unsigned short* __restrict__ h,
                                                     const int2* __restrict__ ep,
                                                     const int* __restrict__ offsets,
                                                     const float* __restrict__ b,
                                                     float* __restrict__ out) {
    int t    = blockIdx.x * blockDim.x + threadIdx.x;
    int node = t >> 4;
    int lane = t & 15;
    if (node >= M_NODES) return;
    int beg = offsets[node];
    int end = offsets[node + 1];

    float4 b0 = *(const float4*)&b[lane * 8];
    float4 b1 = *(const float4*)&b[lane * 8 + 4];
    float a[4][8];
#pragma unroll
    for (int u = 0; u < 4; ++u)
#pragma unroll
        for (int c = 0; c < 8; ++c) a[u][c] = 0.f;

    int j = beg;
    for (; j + 4 <= end; j += 4) {
        int2 e0 = ep[j], e1 = ep[j + 1], e2 = ep[j + 2], e3 = ep[j + 3];
        uint4 q0 = *(const uint4*)(h + (size_t)e0.x * D_OUT_N + lane * 8);
        uint4 q1 = *(const uint4*)(h + (size_t)e1.x * D_OUT_N + lane * 8);
        uint4 q2 = *(const uint4*)(h + (size_t)e2.x * D_OUT_N + lane * 8);
        uint4 q3 = *(const uint4*)(h + (size_t)e3.x * D_OUT_N + lane * 8);
        float w0 = __int_as_float(e0.y), w1 = __int_as_float(e1.y);
        float w2 = __int_as_float(e2.y), w3 = __int_as_float(e3.y);
        a[0][0] += w0 * bflo(q0.x);  a[0][1] += w0 * bfhi(q0.x);
        a[0][2] += w0 * bflo(q0.y);  a[0][3] += w0 * bfhi(q0.y);
        a[0][4] += w0 * bflo(q0.z);  a[0][5] += w0 * bfhi(q0.z);
        a[0][6] += w0 * bflo(q0.w);  a[0][7] += w0 * bfhi(q0.w);
        a[1][0] += w1 * bflo(q1.x);  a[1][1] += w1 * bfhi(q1.x);
        a[1][2] += w1 * bflo(q1.y);  a[1][3] += w1 * bfhi(q1.y);
        a[1][4] += w1 * bflo(q1.z);  a[1][5] += w1 * bfhi(q1.z);
        a[1][6] += w1 * bflo(q1.w);  a[1][7] += w1 * bfhi(q1.w);
        a[2][0] += w2 * bflo(q2.x);  a[2][1] += w2 * bfhi(q2.x);
        a[2][2] += w2 * bflo(q2.y);  a[2][3] += w2 * bfhi(q2.y);
        a[2][4] += w2 * bflo(q2.z);  a[2][5] += w2 * bfhi(q2.z);
        a[2][6] += w2 * bflo(q2.w);  a[2][7] += w2 * bfhi(q2.w);
        a[3][0] += w3 * bflo(q3.x);  a[3][1] += w3 * bfhi(q3.x);
        a[3][2] += w3 * bflo(q3.y);  a[3][3] += w3 * bfhi(q3.y);
        a[3][4] += w3 * bflo(q3.z);  a[3][5] += w3 * bfhi(q3.z);
        a[3][6] += w3 * bflo(q3.w);  a[3][7] += w3 * bfhi(q3.w);
    }
    for (; j < end; ++j) {
        int2 e0 = ep[j];
        float w0 = __int_as_float(e0.y);
        uint4 q0 = *(const uint4*)(h + (size_t)e0.x * D_OUT_N + lane * 8);
        a[0][0] += w0 * bflo(q0.x);  a[0][1] += w0 * bfhi(q0.x);
        a[0][2] += w0 * bflo(q0.y);  a[0][3] += w0 * bfhi(q0.y);
        a[0][4] += w0 * bflo(q0.z);  a[0][5] += w0 * bfhi(q0.z);
        a[0][6] += w0 * bflo(q0.w);  a[0][7] += w0 * bfhi(q0.w);
    }

    float4 o0 = make_float4(b0.x + a[0][0] + a[1][0] + a[2][0] + a[3][0],
                            b0.y + a[0][1] + a[1][1] + a[2][1] + a[3][1],
                            b0.z + a[0][2] + a[1][2] + a[2][2] + a[3][2],
                            b0.w + a[0][3] + a[1][3] + a[2][3] + a[3][3]);
    float4 o1 = make_float4(b1.x + a[0][4] + a[1][4] + a[2][4] + a[3][4],
                            b1.y + a[0][5] + a[1][5] + a[2][5] + a[3][5],
                            b1.z + a[0][6] + a[1][6] + a[2][6] + a[3][6],
                            b1.w + a[0][7] + a[1][7] + a[2][7] + a[3][7]);
    float* op = &out[(size_t)node * D_OUT_N + lane * 8];
    *(float4*)op = o0;
    *(float4*)(op + 4) = o1;
}

extern "C" void kernel_launch(void* const* d_in, const int* in_sizes, int n_in,
                              void* d_out, int out_size, void* d_ws, size_t ws_size,
                              hipStream_t stream) {
    const float* x      = (const float*)d_in[0];
    const float* edge_w = (const float*)d_in[1];
    const int*   src    = (const int*)d_in[2];
    const int*   dst    = (const int*)d_in[3];
    const float* W      = (const float*)d_in[4];
    const float* b      = (const float*)d_in[5];
    float* out = (float*)d_out;

    char* wsp = (char*)d_ws;
    unsigned short* h = (unsigned short*)wsp;  wsp += (size_t)M_NODES * D_OUT_N * 2;      // 12.8 MB
    int*   counts   = (int*)wsp;         wsp += (size_t)M_NODES * 4;                      // 200 KB
    int*   flags    = (int*)wsp;         wsp += 64 * 4;                                   // 256 B (zeroed w/ counts)
    int*   offsets  = (int*)wsp;         wsp += (((size_t)M_NODES + 1) * 4 + 15) & ~15ull;
    int*   rank     = (int*)wsp;         wsp += (size_t)N_EDGES * 4;                      // 3.2 MB
    int2*  ep       = (int2*)wsp;        wsp += (size_t)N_EDGES * 8;                      // 6.4 MB
    unsigned short* Wp = (unsigned short*)wsp; wsp += (size_t)16 * 8 * 64 * 8 * 2;        // 128 KB
    int*   partials = (int*)wsp;         wsp += (SCAN_NBLK * 4 + 15) & ~15ull;

    permw_kernel<<<32, 256, 0, stream>>>(W, Wp, counts);   // also zeroes counts+flags
    mfma_gemm_hist_kernel<<<(M_NODES + 127) / 128, 512, 0, stream>>>(
        x, (const uint4*)Wp, h, dst, counts, rank);
    scan_kernel<<<SCAN_NBLK, 256, 0, stream>>>(counts, offsets, partials, flags);
    fill_kernel<<<(N_EDGES / 4 + 255) / 256, 256, 0, stream>>>(src, dst, edge_w, rank, offsets, ep);
    gather_kernel<<<(int)(((long long)M_NODES * 16 + 255) / 256), 256, 0, stream>>>(
        h, ep, offsets, b, out);
}